// Round 8
// baseline (353.289 us; speedup 1.0000x reference)
//
#include <hip/hip_runtime.h>

#define NN 100000
#define EE 1600000
#define CH 128

typedef _Float16 h2 __attribute__((ext_vector_type(2)));
typedef _Float16 h8 __attribute__((ext_vector_type(8)));
typedef float f32x4 __attribute__((ext_vector_type(4)));

// bucketed CSR build params
#define S_NODES 512
#define NBUCK 196
#define CAP_E 10240

// chunk-split feature layout: element (n, ch) lives at
//   [ (ch>>4) * (NN*16) + n*16 + (ch&15) ]
#define CHUNK_STRIDE ((size_t)NN * 16)

// ---------------- Pass A: partition edges into dst-buckets ----------------

__global__ __launch_bounds__(256) void k_passA(const int* __restrict__ src, const int* __restrict__ dst,
                                               int* __restrict__ gcur, int* __restrict__ eb) {
    __shared__ int hist[NBUCK];
    __shared__ int curL[NBUCK];
    for (int t = threadIdx.x; t < NBUCK; t += 256) hist[t] = 0;
    __syncthreads();
    int base = blockIdx.x * 4096;
    int pk[16], bk[16];
#pragma unroll
    for (int j = 0; j < 16; ++j) {
        int i = base + threadIdx.x + 256 * j;
        if (i < EE) {
            int s = src[i], d = dst[i];
            bk[j] = d >> 9;
            pk[j] = (s << 9) | (d & 511);
            atomicAdd(&hist[bk[j]], 1);
        } else bk[j] = -1;
    }
    __syncthreads();
    for (int t = threadIdx.x; t < NBUCK; t += 256) {
        int h = hist[t];
        curL[t] = (h > 0) ? atomicAdd(&gcur[t], h) : 0;
    }
    __syncthreads();
#pragma unroll
    for (int j = 0; j < 16; ++j) {
        if (bk[j] >= 0) {
            int pos = atomicAdd(&curL[bk[j]], 1);
            if (pos < CAP_E) eb[bk[j] * CAP_E + pos] = pk[j];
        }
    }
}

// ---------------- bucket-base scan ----------------

__global__ __launch_bounds__(256) void k_bscan(const int* __restrict__ gcur, int* __restrict__ bbase,
                                               int* __restrict__ rp) {
    __shared__ int ts[256];
    int t = threadIdx.x;
    int nn = (t < NBUCK) ? min(S_NODES, NN - t * S_NODES) : 0;
    int v = (t < NBUCK) ? (min(gcur[t], CAP_E) + nn) : 0;
    ts[t] = v; __syncthreads();
    for (int off = 1; off < 256; off <<= 1) {
        int u = (t >= off) ? ts[t - off] : 0;
        __syncthreads();
        ts[t] += u;
        __syncthreads();
    }
    if (t < NBUCK) bbase[t] = ts[t] - v;
    if (t == 0) rp[NN] = EE + NN;
}

// ---------------- fused Pass B (+ deg output) ----------------

__global__ __launch_bounds__(256) void k_passB(const int* __restrict__ gcur, const int* __restrict__ eb,
                                               const int* __restrict__ bbase, int* __restrict__ rp,
                                               float* __restrict__ dinv, int* __restrict__ col,
                                               int* __restrict__ deg) {
    __shared__ int c[S_NODES];
    __shared__ int excl[S_NODES];
    __shared__ int cur[S_NODES];
    __shared__ int ts[256];
    __shared__ int stage[CAP_E + S_NODES];
    int bId = blockIdx.x;
    int nbase = bId * S_NODES;
    int tid = threadIdx.x;
    c[tid] = 0; c[tid + 256] = 0;
    __syncthreads();
    int n = min(gcur[bId], CAP_E);
    const int* e = eb + (size_t)bId * CAP_E;
    for (int i = tid; i < n; i += 256) atomicAdd(&c[e[i] & 511], 1);
    __syncthreads();
    int n0 = nbase + 2 * tid, n1 = n0 + 1;
    int v0 = (n0 < NN) ? c[2 * tid] + 1 : 0;
    int v1 = (n1 < NN) ? c[2 * tid + 1] + 1 : 0;
    int s = v0 + v1;
    ts[tid] = s; __syncthreads();
    for (int off = 1; off < 256; off <<= 1) {
        int u = (tid >= off) ? ts[tid - off] : 0;
        __syncthreads();
        ts[tid] += u;
        __syncthreads();
    }
    int ex = ts[tid] - s;
    int base = bbase[bId];
    excl[2 * tid] = ex; excl[2 * tid + 1] = ex + v0;
    cur[2 * tid] = ex;  cur[2 * tid + 1] = ex + v0;
    if (n0 < NN) { rp[n0] = base + ex;      dinv[n0] = rsqrtf((float)v0); deg[n0] = v0; }
    if (n1 < NN) { rp[n1] = base + ex + v0; dinv[n1] = rsqrtf((float)v1); deg[n1] = v1; }
    __syncthreads();
    for (int i = tid; i < n; i += 256) {
        int pe = e[i];
        int pos = atomicAdd(&cur[pe & 511], 1);
        stage[pos] = pe >> 9;
    }
    {
        int t0 = 2 * tid, t1 = 2 * tid + 1;
        if (n0 < NN) stage[excl[t0] + c[t0]] = n0;
        if (n1 < NN) stage[excl[t1] + c[t1]] = n1;
    }
    __syncthreads();
    int total = ts[255];
    for (int i = tid; i < total; i += 256) col[base + i] = stage[i];
}

// ---------------- degree counting sort: hist -> scan -> scatter ----------------

__global__ __launch_bounds__(256) void k_dhist(const int* __restrict__ deg, int* __restrict__ ghist) {
    __shared__ int lh[64];
    int tid = threadIdx.x;
    if (tid < 64) lh[tid] = 0;
    __syncthreads();
    int node = blockIdx.x * 256 + tid;
    if (node < NN) atomicAdd(&lh[min(deg[node], 63)], 1);
    __syncthreads();
    if (tid < 64 && lh[tid] > 0) atomicAdd(&ghist[tid], lh[tid]);
}

__global__ __launch_bounds__(64) void k_dscan(const int* __restrict__ ghist, int* __restrict__ gcur) {
    __shared__ int ts[64];
    int t = threadIdx.x;
    int v = ghist[t];
    ts[t] = v; __syncthreads();
    for (int off = 1; off < 64; off <<= 1) {
        int u = (t >= off) ? ts[t - off] : 0;
        __syncthreads();
        ts[t] += u;
        __syncthreads();
    }
    gcur[t] = ts[t] - v;
}

__global__ __launch_bounds__(256) void k_dsort(const int* __restrict__ deg, int* __restrict__ gcur,
                                               int* __restrict__ perm) {
    __shared__ int lh[64];
    __shared__ int lbase[64];
    int tid = threadIdx.x;
    if (tid < 64) lh[tid] = 0;
    __syncthreads();
    int node = blockIdx.x * 256 + tid;
    int d = -1, lr = 0;
    if (node < NN) {
        d = min(deg[node], 63);
        lr = atomicAdd(&lh[d], 1);
    }
    __syncthreads();
    if (tid < 64) lbase[tid] = (lh[tid] > 0) ? atomicAdd(&gcur[tid], lh[tid]) : 0;
    __syncthreads();
    if (node < NN) perm[lbase[d] + lr] = node;
}

// ---------------- prep: W1,W2 -> fp16 transposed; BN folds ----------------

__global__ __launch_bounds__(128) void k_prep(const float* __restrict__ W1, const float* __restrict__ W2,
                                              _Float16* __restrict__ Wt1, _Float16* __restrict__ Wt2,
                                              const float* __restrict__ b1, const float* __restrict__ g1,
                                              const float* __restrict__ be1, const float* __restrict__ rm1,
                                              const float* __restrict__ rv1,
                                              const float* __restrict__ b2, const float* __restrict__ g2,
                                              const float* __restrict__ be2, const float* __restrict__ rm2,
                                              const float* __restrict__ rv2,
                                              float* __restrict__ sc1, float* __restrict__ sh1,
                                              float* __restrict__ sc2, float* __restrict__ sh2) {
    int bid = blockIdx.x, t = threadIdx.x;
    if (bid < 128) {
        Wt1[bid * 128 + t] = (_Float16)W1[t * 128 + bid];
    } else if (bid < 256) {
        int nn = bid - 128;
        Wt2[nn * 128 + t] = (_Float16)W2[t * 128 + nn];
    } else if (bid == 256) {
        float sv = g1[t] * rsqrtf(rv1[t] + 1e-5f);
        sc1[t] = sv;
        sh1[t] = (b1[t] - rm1[t]) * sv + be1[t];
    } else {
        float sv = g2[t] * rsqrtf(rv2[t] + 1e-5f);
        sc2[t] = sv;
        sh2[t] = (b2[t] - rm2[t]) * sv + be2[t];
    }
}

// ---------------- MFMA GEMM [N,128]@[128,128] ----------------

template <bool F32IN>
__global__ __launch_bounds__(256) void k_gemm_mfma(const void* __restrict__ Ain,
                                                   const _Float16* __restrict__ Wt,
                                                   const float* __restrict__ dinv,
                                                   _Float16* __restrict__ C) {
    __shared__ _Float16 Wl[CH * CH];  // 32 KB, [row][16B-slot XOR-swizzled]
    {
        const float4* wg = (const float4*)Wt;
#pragma unroll
        for (int i = 0; i < 8; ++i) {
            int chunk = i * 256 + threadIdx.x;
            int row = chunk >> 4, slot = chunk & 15;
            float4 v = wg[chunk];
            *(float4*)((char*)Wl + row * 256 + ((slot ^ (row & 15)) * 16)) = v;
        }
    }
    __syncthreads();
    int lane = threadIdx.x & 63;
    int l15 = lane & 15, lhi = lane >> 4;
    int row0 = blockIdx.x * 64 + (threadIdx.x >> 6) * 16;
    if (row0 >= NN) return;

    h8 afrag[4];
    if (F32IN) {
        const float* Arow = (const float*)Ain + (size_t)(row0 + l15) * CH + lhi * 8;
#pragma unroll
        for (int ks = 0; ks < 4; ++ks) {
            float4 a = *(const float4*)(Arow + ks * 32);
            float4 b = *(const float4*)(Arow + ks * 32 + 4);
            h8 o;
            o[0] = (_Float16)a.x; o[1] = (_Float16)a.y; o[2] = (_Float16)a.z; o[3] = (_Float16)a.w;
            o[4] = (_Float16)b.x; o[5] = (_Float16)b.y; o[6] = (_Float16)b.z; o[7] = (_Float16)b.w;
            afrag[ks] = o;
        }
    } else {
        const _Float16* Ah = (const _Float16*)Ain;
#pragma unroll
        for (int ks = 0; ks < 4; ++ks) {
            int chunk = ks * 2 + (lhi >> 1);
            afrag[ks] = *(const h8*)(Ah + (size_t)chunk * CHUNK_STRIDE
                                     + (size_t)(row0 + l15) * 16 + (lhi & 1) * 8);
        }
    }

    f32x4 acc[8] = {};
#pragma unroll
    for (int ks = 0; ks < 4; ++ks) {
        int slot = ks * 4 + lhi;
#pragma unroll
        for (int c = 0; c < 8; ++c) {
            int brow = c * 16 + l15;
            h8 b = *(const h8*)((char*)Wl + brow * 256 + ((slot ^ (brow & 15)) * 16));
            acc[c] = __builtin_amdgcn_mfma_f32_16x16x32_f16(afrag[ks], b, acc[c], 0, 0, 0);
        }
    }
    float dv[4];
#pragma unroll
    for (int j = 0; j < 4; ++j) dv[j] = dinv[row0 + lhi * 4 + j];
#pragma unroll
    for (int c = 0; c < 8; ++c)
#pragma unroll
        for (int j = 0; j < 4; ++j) {
            float v = acc[c][j] * dv[j];
            C[(size_t)c * CHUNK_STRIDE + (size_t)(row0 + lhi * 4 + j) * 16 + l15] = (_Float16)v;
        }
}

// ---------------- XCD-sliced aggregation v4 ----------------
// Slice s = blockIdx.x & 7 -> fixed XCD (3.2 MB table L2-resident).
// Wave = 32 degree-sorted nodes (via perm) x 2 lanes; lane gathers h8 (16B = 8ch).
// Degree sort -> wave-max deg ~ mean (padding ~1.05). col padded: no addr clamp,
// out-of-range slots read valid next-node edges, masked in the fma.

#define UNROLL 8

__global__ __launch_bounds__(256) void k_aggs4(const _Float16* __restrict__ h, const int* __restrict__ rp,
                                               const int* __restrict__ col, const int* __restrict__ perm,
                                               const float* __restrict__ dinv,
                                               const float* __restrict__ sc, const float* __restrict__ sh,
                                               _Float16* __restrict__ out) {
    int s = blockIdx.x & 7;
    int gw = (blockIdx.x >> 3) * 4 + (threadIdx.x >> 6);
    int base = gw * 32;
    if (base >= NN) return;
    int lane = threadIdx.x & 63;
    int half = lane & 1;
    int node = perm[base + (lane >> 1)];
    int beg = rp[node], end = rp[node + 1];
    int md = end - beg;
    md = max(md, __shfl_xor(md, 2));
    md = max(md, __shfl_xor(md, 4));
    md = max(md, __shfl_xor(md, 8));
    md = max(md, __shfl_xor(md, 16));
    md = max(md, __shfl_xor(md, 32));
    const _Float16* hs = h + (size_t)s * CHUNK_STRIDE + half * 8;
    float acc[8] = {};
    for (int e = 0; e < md; e += UNROLL) {
        int idx[UNROLL]; float m[UNROLL];
#pragma unroll
        for (int j = 0; j < UNROLL; ++j) {
            int i = beg + e + j;
            idx[j] = col[i];                    // col padded by 64: always safe
            m[j] = (i < end) ? 1.f : 0.f;
        }
        h8 v[UNROLL];
#pragma unroll
        for (int j = 0; j < UNROLL; ++j)
            v[j] = *(const h8*)(hs + ((size_t)idx[j] << 4));
#pragma unroll
        for (int j = 0; j < UNROLL; ++j)
#pragma unroll
            for (int k = 0; k < 8; ++k)
                acc[k] = fmaf((float)v[j][k], m[j], acc[k]);
    }
    float dvn = dinv[node];
    int cb = s * 16 + half * 8;
    float4 s0 = *(const float4*)(sc + cb);
    float4 s1 = *(const float4*)(sc + cb + 4);
    float4 t0 = *(const float4*)(sh + cb);
    float4 t1 = *(const float4*)(sh + cb + 4);
    h8 o;
    o[0] = (_Float16)fmaxf(fmaf(acc[0] * dvn, s0.x, t0.x), 0.f);
    o[1] = (_Float16)fmaxf(fmaf(acc[1] * dvn, s0.y, t0.y), 0.f);
    o[2] = (_Float16)fmaxf(fmaf(acc[2] * dvn, s0.z, t0.z), 0.f);
    o[3] = (_Float16)fmaxf(fmaf(acc[3] * dvn, s0.w, t0.w), 0.f);
    o[4] = (_Float16)fmaxf(fmaf(acc[4] * dvn, s1.x, t1.x), 0.f);
    o[5] = (_Float16)fmaxf(fmaf(acc[5] * dvn, s1.y, t1.y), 0.f);
    o[6] = (_Float16)fmaxf(fmaf(acc[6] * dvn, s1.z, t1.z), 0.f);
    o[7] = (_Float16)fmaxf(fmaf(acc[7] * dvn, s1.w, t1.w), 0.f);
    *(h8*)(out + (size_t)s * CHUNK_STRIDE + (size_t)node * 16 + half * 8) = o;
}

// ---------------- Layer 3 ----------------

__global__ __launch_bounds__(256) void k_gemm_out(const _Float16* __restrict__ A, const float* __restrict__ W3,
                                                  const float* __restrict__ dinv, float* __restrict__ H3) {
    __shared__ float w3s[256];
    w3s[threadIdx.x] = W3[threadIdx.x];
    __syncthreads();
    int n = blockIdx.x * 256 + threadIdx.x;
    if (n >= NN) return;
    float a0 = 0.f, a1 = 0.f;
#pragma unroll
    for (int c = 0; c < 8; ++c) {
        h8 a = *(const h8*)(A + (size_t)c * CHUNK_STRIDE + (size_t)n * 16);
        h8 b = *(const h8*)(A + (size_t)c * CHUNK_STRIDE + (size_t)n * 16 + 8);
#pragma unroll
        for (int j = 0; j < 8; ++j) {
            int k = c * 16 + j;
            a0 += (float)a[j] * w3s[k * 2];
            a1 += (float)a[j] * w3s[k * 2 + 1];
        }
#pragma unroll
        for (int j = 0; j < 8; ++j) {
            int k = c * 16 + 8 + j;
            a0 += (float)b[j] * w3s[k * 2];
            a1 += (float)b[j] * w3s[k * 2 + 1];
        }
    }
    float dv = dinv[n];
    *(float2*)(H3 + (size_t)n * 2) = make_float2(a0 * dv, a1 * dv);
}

__global__ __launch_bounds__(256) void k_agg_out(const float* __restrict__ H3, const int* __restrict__ rp,
                                                 const int* __restrict__ col, const float* __restrict__ dinv,
                                                 const float* __restrict__ b3, float* __restrict__ out) {
    int n = blockIdx.x * 256 + threadIdx.x;
    if (n >= NN) return;
    int beg = rp[n], end = rp[n + 1];
    float a0 = 0.f, a1 = 0.f;
    for (int e = beg; e < end; ++e) {
        int s = col[e];
        float2 hv = *(const float2*)(H3 + (size_t)s * 2);
        a0 += hv.x;
        a1 += hv.y;
    }
    float dv = dinv[n];
    out[(size_t)n * 2 + 0] = fmaf(a0, dv, b3[0]);
    out[(size_t)n * 2 + 1] = fmaf(a1, dv, b3[1]);
}

// ---------------- launch ----------------

extern "C" void kernel_launch(void* const* d_in, const int* in_sizes, int n_in,
                              void* d_out, int out_size, void* d_ws, size_t ws_size,
                              hipStream_t stream) {
    const float* x  = (const float*)d_in[0];
    const int* ei   = (const int*)d_in[1];
    const int* src  = ei;
    const int* dst  = ei + EE;
    const float* W1 = (const float*)d_in[2];
    const float* b1 = (const float*)d_in[3];
    const float* g1 = (const float*)d_in[4];
    const float* be1 = (const float*)d_in[5];
    const float* rm1 = (const float*)d_in[6];
    const float* rv1 = (const float*)d_in[7];
    const float* W2 = (const float*)d_in[8];
    const float* b2 = (const float*)d_in[9];
    const float* g2 = (const float*)d_in[10];
    const float* be2 = (const float*)d_in[11];
    const float* rm2 = (const float*)d_in[12];
    const float* rv2 = (const float*)d_in[13];
    const float* W3 = (const float*)d_in[14];
    const float* b3 = (const float*)d_in[15];
    float* out = (float*)d_out;

    char* p = (char*)d_ws;
    auto carve = [&](size_t bytes) -> void* {
        void* r = (void*)p;
        p += (bytes + 255) & ~(size_t)255;
        return r;
    };
    int* rp     = (int*)carve((size_t)(NN + 1) * 4);
    float* dinv = (float*)carve((size_t)NN * 4);
    int* col    = (int*)carve((size_t)(EE + NN + 64) * 4);
    int* bbase  = (int*)carve(256 * 4);
    int* deg    = (int*)carve((size_t)NN * 4);
    int* perm   = (int*)carve((size_t)NN * 4);
    int* ghist  = (int*)carve(64 * 4);
    int* dcur   = (int*)carve(64 * 4);
    float* sc1  = (float*)carve(128 * 4);
    float* sh1  = (float*)carve(128 * 4);
    float* sc2  = (float*)carve(128 * 4);
    float* sh2  = (float*)carve(128 * 4);
    _Float16* bufA = (_Float16*)carve((size_t)NN * CH * 2);
    _Float16* bufB = (_Float16*)carve((size_t)NN * CH * 2);
    _Float16* Wt1  = (_Float16*)carve(128 * 128 * 2);
    _Float16* Wt2  = (_Float16*)carve(128 * 128 * 2);
    float* h3   = (float*)carve((size_t)NN * 2 * 4);

    // bucket workspace aliases bufA (dead until first GEMM)
    int* eb   = (int*)bufA;
    int* gcur = eb + (size_t)NBUCK * CAP_E;

    hipMemsetAsync(gcur, 0, (size_t)NBUCK * 4, stream);
    hipMemsetAsync(ghist, 0, 64 * 4, stream);
    hipMemsetAsync(col + EE + NN, 0, 64 * 4, stream);

    int nblk = (NN + 255) / 256;
    k_passA<<<(EE + 4095) / 4096, 256, 0, stream>>>(src, dst, gcur, eb);
    k_bscan<<<1, 256, 0, stream>>>(gcur, bbase, rp);
    k_passB<<<NBUCK, 256, 0, stream>>>(gcur, eb, bbase, rp, dinv, col, deg);
    k_dhist<<<nblk, 256, 0, stream>>>(deg, ghist);
    k_dscan<<<1, 64, 0, stream>>>(ghist, dcur);
    k_dsort<<<nblk, 256, 0, stream>>>(deg, dcur, perm);
    k_prep<<<258, 128, 0, stream>>>(W1, W2, Wt1, Wt2,
                                    b1, g1, be1, rm1, rv1,
                                    b2, g2, be2, rm2, rv2,
                                    sc1, sh1, sc2, sh2);

    int aggBlocks = 8 * ((NN / 32 + 3) / 4);
    k_gemm_mfma<true><<<(NN + 63) / 64, 256, 0, stream>>>(x, Wt1, dinv, bufA);
    k_aggs4<<<aggBlocks, 256, 0, stream>>>(bufA, rp, col, perm, dinv, sc1, sh1, bufB);
    k_gemm_mfma<false><<<(NN + 63) / 64, 256, 0, stream>>>(bufB, Wt2, dinv, bufA);
    k_aggs4<<<aggBlocks, 256, 0, stream>>>(bufA, rp, col, perm, dinv, sc2, sh2, bufB);
    k_gemm_out<<<(NN + 255) / 256, 256, 0, stream>>>(bufB, W3, dinv, h3);
    k_agg_out<<<(NN + 255) / 256, 256, 0, stream>>>(h3, rp, col, dinv, b3, out);
}

// Round 9
// 327.843 us; speedup vs baseline: 1.0776x; 1.0776x over previous
//
#include <hip/hip_runtime.h>

#define NN 100000
#define EE 1600000
#define CH 128

typedef _Float16 h2 __attribute__((ext_vector_type(2)));
typedef _Float16 h8 __attribute__((ext_vector_type(8)));
typedef float f32x4 __attribute__((ext_vector_type(4)));

// bucketed CSR build params
#define S_NODES 512
#define NBUCK 196
#define CAP_E 10240

// chunk-split feature layout: element (n, ch) lives at
//   [ (ch>>4) * (NN*16) + n*16 + (ch&15) ]
#define CHUNK_STRIDE ((size_t)NN * 16)

// ---------------- Pass A: partition edges into dst-buckets ----------------

__global__ __launch_bounds__(256) void k_passA(const int* __restrict__ src, const int* __restrict__ dst,
                                               int* __restrict__ gcur, int* __restrict__ eb) {
    __shared__ int hist[NBUCK];
    __shared__ int curL[NBUCK];
    for (int t = threadIdx.x; t < NBUCK; t += 256) hist[t] = 0;
    __syncthreads();
    int base = blockIdx.x * 4096;
    int pk[16], bk[16];
#pragma unroll
    for (int j = 0; j < 16; ++j) {
        int i = base + threadIdx.x + 256 * j;
        if (i < EE) {
            int s = src[i], d = dst[i];
            bk[j] = d >> 9;
            pk[j] = (s << 9) | (d & 511);
            atomicAdd(&hist[bk[j]], 1);
        } else bk[j] = -1;
    }
    __syncthreads();
    for (int t = threadIdx.x; t < NBUCK; t += 256) {
        int h = hist[t];
        curL[t] = (h > 0) ? atomicAdd(&gcur[t], h) : 0;
    }
    __syncthreads();
#pragma unroll
    for (int j = 0; j < 16; ++j) {
        if (bk[j] >= 0) {
            int pos = atomicAdd(&curL[bk[j]], 1);
            if (pos < CAP_E) eb[bk[j] * CAP_E + pos] = pk[j];
        }
    }
}

// ---------------- bucket-base scan ----------------

__global__ __launch_bounds__(256) void k_bscan(const int* __restrict__ gcur, int* __restrict__ bbase,
                                               int* __restrict__ rp) {
    __shared__ int ts[256];
    int t = threadIdx.x;
    int nn = (t < NBUCK) ? min(S_NODES, NN - t * S_NODES) : 0;
    int v = (t < NBUCK) ? (min(gcur[t], CAP_E) + nn) : 0;
    ts[t] = v; __syncthreads();
    for (int off = 1; off < 256; off <<= 1) {
        int u = (t >= off) ? ts[t - off] : 0;
        __syncthreads();
        ts[t] += u;
        __syncthreads();
    }
    if (t < NBUCK) bbase[t] = ts[t] - v;
    if (t == 0) rp[NN] = EE + NN;
}

// ---------------- fused Pass B (+ deg output) ----------------

__global__ __launch_bounds__(256) void k_passB(const int* __restrict__ gcur, const int* __restrict__ eb,
                                               const int* __restrict__ bbase, int* __restrict__ rp,
                                               float* __restrict__ dinv, int* __restrict__ col,
                                               int* __restrict__ deg) {
    __shared__ int c[S_NODES];
    __shared__ int excl[S_NODES];
    __shared__ int cur[S_NODES];
    __shared__ int ts[256];
    __shared__ int stage[CAP_E + S_NODES];
    int bId = blockIdx.x;
    int nbase = bId * S_NODES;
    int tid = threadIdx.x;
    c[tid] = 0; c[tid + 256] = 0;
    __syncthreads();
    int n = min(gcur[bId], CAP_E);
    const int* e = eb + (size_t)bId * CAP_E;
    for (int i = tid; i < n; i += 256) atomicAdd(&c[e[i] & 511], 1);
    __syncthreads();
    int n0 = nbase + 2 * tid, n1 = n0 + 1;
    int v0 = (n0 < NN) ? c[2 * tid] + 1 : 0;
    int v1 = (n1 < NN) ? c[2 * tid + 1] + 1 : 0;
    int s = v0 + v1;
    ts[tid] = s; __syncthreads();
    for (int off = 1; off < 256; off <<= 1) {
        int u = (tid >= off) ? ts[tid - off] : 0;
        __syncthreads();
        ts[tid] += u;
        __syncthreads();
    }
    int ex = ts[tid] - s;
    int base = bbase[bId];
    excl[2 * tid] = ex; excl[2 * tid + 1] = ex + v0;
    cur[2 * tid] = ex;  cur[2 * tid + 1] = ex + v0;
    if (n0 < NN) { rp[n0] = base + ex;      dinv[n0] = rsqrtf((float)v0); deg[n0] = v0; }
    if (n1 < NN) { rp[n1] = base + ex + v0; dinv[n1] = rsqrtf((float)v1); deg[n1] = v1; }
    __syncthreads();
    for (int i = tid; i < n; i += 256) {
        int pe = e[i];
        int pos = atomicAdd(&cur[pe & 511], 1);
        stage[pos] = pe >> 9;
    }
    {
        int t0 = 2 * tid, t1 = 2 * tid + 1;
        if (n0 < NN) stage[excl[t0] + c[t0]] = n0;
        if (n1 < NN) stage[excl[t1] + c[t1]] = n1;
    }
    __syncthreads();
    int total = ts[255];
    for (int i = tid; i < total; i += 256) col[base + i] = stage[i];
}

// ---------------- windowed degree sort: counting sort within 2048-node windows ----
// Preserves spatial locality (wave's nodes stay in one window -> col/rp/write
// footprint compact, L2 keeps the gather table) while equalizing in-wave degree.

#define WIN 2048

__global__ __launch_bounds__(256) void k_wsort(const int* __restrict__ deg, int* __restrict__ perm) {
    __shared__ int lh[64];
    __shared__ int lbase[64];
    int wbase = blockIdx.x * WIN;
    int tid = threadIdx.x;
    if (tid < 64) lh[tid] = 0;
    __syncthreads();
    int d[8], lr[8];
#pragma unroll
    for (int j = 0; j < 8; ++j) {
        int node = wbase + tid + 256 * j;
        if (node < NN) {
            d[j] = min(deg[node], 63);
            lr[j] = atomicAdd(&lh[d[j]], 1);
        } else d[j] = -1;
    }
    __syncthreads();
    if (tid == 0) {
        int run = 0;
#pragma unroll
        for (int i = 0; i < 64; ++i) { lbase[i] = run; run += lh[i]; }
    }
    __syncthreads();
#pragma unroll
    for (int j = 0; j < 8; ++j) {
        if (d[j] >= 0) {
            int node = wbase + tid + 256 * j;
            perm[wbase + lbase[d[j]] + lr[j]] = node;
        }
    }
}

// ---------------- prep: W1,W2 -> fp16 transposed; BN folds ----------------

__global__ __launch_bounds__(128) void k_prep(const float* __restrict__ W1, const float* __restrict__ W2,
                                              _Float16* __restrict__ Wt1, _Float16* __restrict__ Wt2,
                                              const float* __restrict__ b1, const float* __restrict__ g1,
                                              const float* __restrict__ be1, const float* __restrict__ rm1,
                                              const float* __restrict__ rv1,
                                              const float* __restrict__ b2, const float* __restrict__ g2,
                                              const float* __restrict__ be2, const float* __restrict__ rm2,
                                              const float* __restrict__ rv2,
                                              float* __restrict__ sc1, float* __restrict__ sh1,
                                              float* __restrict__ sc2, float* __restrict__ sh2) {
    int bid = blockIdx.x, t = threadIdx.x;
    if (bid < 128) {
        Wt1[bid * 128 + t] = (_Float16)W1[t * 128 + bid];
    } else if (bid < 256) {
        int nn = bid - 128;
        Wt2[nn * 128 + t] = (_Float16)W2[t * 128 + nn];
    } else if (bid == 256) {
        float sv = g1[t] * rsqrtf(rv1[t] + 1e-5f);
        sc1[t] = sv;
        sh1[t] = (b1[t] - rm1[t]) * sv + be1[t];
    } else {
        float sv = g2[t] * rsqrtf(rv2[t] + 1e-5f);
        sc2[t] = sv;
        sh2[t] = (b2[t] - rm2[t]) * sv + be2[t];
    }
}

// ---------------- MFMA GEMM [N,128]@[128,128] ----------------

template <bool F32IN>
__global__ __launch_bounds__(256) void k_gemm_mfma(const void* __restrict__ Ain,
                                                   const _Float16* __restrict__ Wt,
                                                   const float* __restrict__ dinv,
                                                   _Float16* __restrict__ C) {
    __shared__ _Float16 Wl[CH * CH];  // 32 KB, [row][16B-slot XOR-swizzled]
    {
        const float4* wg = (const float4*)Wt;
#pragma unroll
        for (int i = 0; i < 8; ++i) {
            int chunk = i * 256 + threadIdx.x;
            int row = chunk >> 4, slot = chunk & 15;
            float4 v = wg[chunk];
            *(float4*)((char*)Wl + row * 256 + ((slot ^ (row & 15)) * 16)) = v;
        }
    }
    __syncthreads();
    int lane = threadIdx.x & 63;
    int l15 = lane & 15, lhi = lane >> 4;
    int row0 = blockIdx.x * 64 + (threadIdx.x >> 6) * 16;
    if (row0 >= NN) return;

    h8 afrag[4];
    if (F32IN) {
        const float* Arow = (const float*)Ain + (size_t)(row0 + l15) * CH + lhi * 8;
#pragma unroll
        for (int ks = 0; ks < 4; ++ks) {
            float4 a = *(const float4*)(Arow + ks * 32);
            float4 b = *(const float4*)(Arow + ks * 32 + 4);
            h8 o;
            o[0] = (_Float16)a.x; o[1] = (_Float16)a.y; o[2] = (_Float16)a.z; o[3] = (_Float16)a.w;
            o[4] = (_Float16)b.x; o[5] = (_Float16)b.y; o[6] = (_Float16)b.z; o[7] = (_Float16)b.w;
            afrag[ks] = o;
        }
    } else {
        const _Float16* Ah = (const _Float16*)Ain;
#pragma unroll
        for (int ks = 0; ks < 4; ++ks) {
            int chunk = ks * 2 + (lhi >> 1);
            afrag[ks] = *(const h8*)(Ah + (size_t)chunk * CHUNK_STRIDE
                                     + (size_t)(row0 + l15) * 16 + (lhi & 1) * 8);
        }
    }

    f32x4 acc[8] = {};
#pragma unroll
    for (int ks = 0; ks < 4; ++ks) {
        int slot = ks * 4 + lhi;
#pragma unroll
        for (int c = 0; c < 8; ++c) {
            int brow = c * 16 + l15;
            h8 b = *(const h8*)((char*)Wl + brow * 256 + ((slot ^ (brow & 15)) * 16));
            acc[c] = __builtin_amdgcn_mfma_f32_16x16x32_f16(afrag[ks], b, acc[c], 0, 0, 0);
        }
    }
    float dv[4];
#pragma unroll
    for (int j = 0; j < 4; ++j) dv[j] = dinv[row0 + lhi * 4 + j];
#pragma unroll
    for (int c = 0; c < 8; ++c)
#pragma unroll
        for (int j = 0; j < 4; ++j) {
            float v = acc[c][j] * dv[j];
            C[(size_t)c * CHUNK_STRIDE + (size_t)(row0 + lhi * 4 + j) * 16 + l15] = (_Float16)v;
        }
}

// ---------------- XCD-sliced aggregation v4 (windowed-sorted perm) ----------------
// Slice s = blockIdx.x & 7 -> fixed XCD (3.2 MB table L2-resident).
// Wave = 32 degree-similar nodes from ONE 2048-window x 2 lanes; lane gathers h8.

#define UNROLL 8

__global__ __launch_bounds__(256) void k_aggs4(const _Float16* __restrict__ h, const int* __restrict__ rp,
                                               const int* __restrict__ col, const int* __restrict__ perm,
                                               const float* __restrict__ dinv,
                                               const float* __restrict__ sc, const float* __restrict__ sh,
                                               _Float16* __restrict__ out) {
    int s = blockIdx.x & 7;
    int gw = (blockIdx.x >> 3) * 4 + (threadIdx.x >> 6);
    int base = gw * 32;
    if (base >= NN) return;
    int lane = threadIdx.x & 63;
    int half = lane & 1;
    int node = perm[base + (lane >> 1)];
    int beg = rp[node], end = rp[node + 1];
    int md = end - beg;
    md = max(md, __shfl_xor(md, 2));
    md = max(md, __shfl_xor(md, 4));
    md = max(md, __shfl_xor(md, 8));
    md = max(md, __shfl_xor(md, 16));
    md = max(md, __shfl_xor(md, 32));
    const _Float16* hs = h + (size_t)s * CHUNK_STRIDE + half * 8;
    float acc[8] = {};
    for (int e = 0; e < md; e += UNROLL) {
        int idx[UNROLL]; float m[UNROLL];
#pragma unroll
        for (int j = 0; j < UNROLL; ++j) {
            int i = beg + e + j;
            idx[j] = col[i];                    // col padded by 64: always safe
            m[j] = (i < end) ? 1.f : 0.f;
        }
        h8 v[UNROLL];
#pragma unroll
        for (int j = 0; j < UNROLL; ++j)
            v[j] = *(const h8*)(hs + ((size_t)idx[j] << 4));
#pragma unroll
        for (int j = 0; j < UNROLL; ++j)
#pragma unroll
            for (int k = 0; k < 8; ++k)
                acc[k] = fmaf((float)v[j][k], m[j], acc[k]);
    }
    float dvn = dinv[node];
    int cb = s * 16 + half * 8;
    float4 s0 = *(const float4*)(sc + cb);
    float4 s1 = *(const float4*)(sc + cb + 4);
    float4 t0 = *(const float4*)(sh + cb);
    float4 t1 = *(const float4*)(sh + cb + 4);
    h8 o;
    o[0] = (_Float16)fmaxf(fmaf(acc[0] * dvn, s0.x, t0.x), 0.f);
    o[1] = (_Float16)fmaxf(fmaf(acc[1] * dvn, s0.y, t0.y), 0.f);
    o[2] = (_Float16)fmaxf(fmaf(acc[2] * dvn, s0.z, t0.z), 0.f);
    o[3] = (_Float16)fmaxf(fmaf(acc[3] * dvn, s0.w, t0.w), 0.f);
    o[4] = (_Float16)fmaxf(fmaf(acc[4] * dvn, s1.x, t1.x), 0.f);
    o[5] = (_Float16)fmaxf(fmaf(acc[5] * dvn, s1.y, t1.y), 0.f);
    o[6] = (_Float16)fmaxf(fmaf(acc[6] * dvn, s1.z, t1.z), 0.f);
    o[7] = (_Float16)fmaxf(fmaf(acc[7] * dvn, s1.w, t1.w), 0.f);
    *(h8*)(out + (size_t)s * CHUNK_STRIDE + (size_t)node * 16 + half * 8) = o;
}

// ---------------- Layer 3 ----------------

__global__ __launch_bounds__(256) void k_gemm_out(const _Float16* __restrict__ A, const float* __restrict__ W3,
                                                  const float* __restrict__ dinv, float* __restrict__ H3) {
    __shared__ float w3s[256];
    w3s[threadIdx.x] = W3[threadIdx.x];
    __syncthreads();
    int n = blockIdx.x * 256 + threadIdx.x;
    if (n >= NN) return;
    float a0 = 0.f, a1 = 0.f;
#pragma unroll
    for (int c = 0; c < 8; ++c) {
        h8 a = *(const h8*)(A + (size_t)c * CHUNK_STRIDE + (size_t)n * 16);
        h8 b = *(const h8*)(A + (size_t)c * CHUNK_STRIDE + (size_t)n * 16 + 8);
#pragma unroll
        for (int j = 0; j < 8; ++j) {
            int k = c * 16 + j;
            a0 += (float)a[j] * w3s[k * 2];
            a1 += (float)a[j] * w3s[k * 2 + 1];
        }
#pragma unroll
        for (int j = 0; j < 8; ++j) {
            int k = c * 16 + 8 + j;
            a0 += (float)b[j] * w3s[k * 2];
            a1 += (float)b[j] * w3s[k * 2 + 1];
        }
    }
    float dv = dinv[n];
    *(float2*)(H3 + (size_t)n * 2) = make_float2(a0 * dv, a1 * dv);
}

__global__ __launch_bounds__(256) void k_agg_out(const float* __restrict__ H3, const int* __restrict__ rp,
                                                 const int* __restrict__ col, const float* __restrict__ dinv,
                                                 const float* __restrict__ b3, float* __restrict__ out) {
    int n = blockIdx.x * 256 + threadIdx.x;
    if (n >= NN) return;
    int beg = rp[n], end = rp[n + 1];
    float a0 = 0.f, a1 = 0.f;
    for (int e = beg; e < end; ++e) {
        int s = col[e];
        float2 hv = *(const float2*)(H3 + (size_t)s * 2);
        a0 += hv.x;
        a1 += hv.y;
    }
    float dv = dinv[n];
    out[(size_t)n * 2 + 0] = fmaf(a0, dv, b3[0]);
    out[(size_t)n * 2 + 1] = fmaf(a1, dv, b3[1]);
}

// ---------------- launch ----------------

extern "C" void kernel_launch(void* const* d_in, const int* in_sizes, int n_in,
                              void* d_out, int out_size, void* d_ws, size_t ws_size,
                              hipStream_t stream) {
    const float* x  = (const float*)d_in[0];
    const int* ei   = (const int*)d_in[1];
    const int* src  = ei;
    const int* dst  = ei + EE;
    const float* W1 = (const float*)d_in[2];
    const float* b1 = (const float*)d_in[3];
    const float* g1 = (const float*)d_in[4];
    const float* be1 = (const float*)d_in[5];
    const float* rm1 = (const float*)d_in[6];
    const float* rv1 = (const float*)d_in[7];
    const float* W2 = (const float*)d_in[8];
    const float* b2 = (const float*)d_in[9];
    const float* g2 = (const float*)d_in[10];
    const float* be2 = (const float*)d_in[11];
    const float* rm2 = (const float*)d_in[12];
    const float* rv2 = (const float*)d_in[13];
    const float* W3 = (const float*)d_in[14];
    const float* b3 = (const float*)d_in[15];
    float* out = (float*)d_out;

    char* p = (char*)d_ws;
    auto carve = [&](size_t bytes) -> void* {
        void* r = (void*)p;
        p += (bytes + 255) & ~(size_t)255;
        return r;
    };
    int* rp     = (int*)carve((size_t)(NN + 1) * 4);
    float* dinv = (float*)carve((size_t)NN * 4);
    int* col    = (int*)carve((size_t)(EE + NN + 64) * 4);
    int* bbase  = (int*)carve(256 * 4);
    int* deg    = (int*)carve((size_t)NN * 4);
    int* perm   = (int*)carve((size_t)NN * 4);
    float* sc1  = (float*)carve(128 * 4);
    float* sh1  = (float*)carve(128 * 4);
    float* sc2  = (float*)carve(128 * 4);
    float* sh2  = (float*)carve(128 * 4);
    _Float16* bufA = (_Float16*)carve((size_t)NN * CH * 2);
    _Float16* bufB = (_Float16*)carve((size_t)NN * CH * 2);
    _Float16* Wt1  = (_Float16*)carve(128 * 128 * 2);
    _Float16* Wt2  = (_Float16*)carve(128 * 128 * 2);
    float* h3   = (float*)carve((size_t)NN * 2 * 4);

    // bucket workspace aliases bufA (dead until first GEMM)
    int* eb   = (int*)bufA;
    int* gcur = eb + (size_t)NBUCK * CAP_E;

    hipMemsetAsync(gcur, 0, (size_t)NBUCK * 4, stream);
    hipMemsetAsync(col + EE + NN, 0, 64 * 4, stream);

    k_passA<<<(EE + 4095) / 4096, 256, 0, stream>>>(src, dst, gcur, eb);
    k_bscan<<<1, 256, 0, stream>>>(gcur, bbase, rp);
    k_passB<<<NBUCK, 256, 0, stream>>>(gcur, eb, bbase, rp, dinv, col, deg);
    k_wsort<<<(NN + WIN - 1) / WIN, 256, 0, stream>>>(deg, perm);
    k_prep<<<258, 128, 0, stream>>>(W1, W2, Wt1, Wt2,
                                    b1, g1, be1, rm1, rv1,
                                    b2, g2, be2, rm2, rv2,
                                    sc1, sh1, sc2, sh2);

    int aggBlocks = 8 * ((NN / 32 + 3) / 4);
    k_gemm_mfma<true><<<(NN + 63) / 64, 256, 0, stream>>>(x, Wt1, dinv, bufA);
    k_aggs4<<<aggBlocks, 256, 0, stream>>>(bufA, rp, col, perm, dinv, sc1, sh1, bufB);
    k_gemm_mfma<false><<<(NN + 63) / 64, 256, 0, stream>>>(bufB, Wt2, dinv, bufA);
    k_aggs4<<<aggBlocks, 256, 0, stream>>>(bufA, rp, col, perm, dinv, sc2, sh2, bufB);
    k_gemm_out<<<(NN + 255) / 256, 256, 0, stream>>>(bufB, W3, dinv, h3);
    k_agg_out<<<(NN + 255) / 256, 256, 0, stream>>>(h3, rp, col, dinv, b3, out);
}